// Round 3
// baseline (405.646 us; speedup 1.0000x reference)
//
#include <hip/hip_runtime.h>

#define N_NODES 50000
#define NIN 128
#define NOUT 64
#define EIN 32
#define N_EDGES 400000
#define N_UNITS (2 * N_EDGES)
#define ALPHA 0.2f
#define NBINS 16

__device__ __forceinline__ int clampi(int x) {
  return min(max(x, 0), N_NODES - 1);
}

// ---------------------------------------------------------------------------
// Kernel 1: h = node_fts @ W + b (f32), fused A = h.a1, B = h.a2, hn = ||h||.
// One wave per node, lane j = column j.
// ---------------------------------------------------------------------------
__global__ __launch_bounds__(256) void k_gemm(
    const float* __restrict__ nf, const float* __restrict__ W,
    const float* __restrict__ b, const float* __restrict__ a,
    float* __restrict__ h, float* __restrict__ A, float* __restrict__ B,
    float* __restrict__ hn) {
  __shared__ float Ws[NIN * NOUT];  // 32 KB
  __shared__ float bs[NOUT], a1s[NOUT], a2s[NOUT];
  __shared__ float rows[4][NIN];
  int t = threadIdx.x;
#pragma unroll
  for (int n = 0; n < 32; ++n) Ws[t + n * 256] = W[t + n * 256];
  if (t < 64) { bs[t] = b[t]; a1s[t] = a[t]; a2s[t] = a[64 + t]; }
  __syncthreads();
  int j = t & 63, local = t >> 6;
  for (int v0 = blockIdx.x * 4; v0 < N_NODES; v0 += gridDim.x * 4) {
    int vload = v0 + (t >> 6);
    if (vload < N_NODES) {
      float2 p = ((const float2*)(nf + (size_t)vload * NIN))[t & 63];
      ((float2*)rows[t >> 6])[t & 63] = p;
    }
    __syncthreads();
    int v = v0 + local;
    if (v < N_NODES) {
      float acc = bs[j];
      const float* r = rows[local];
#pragma unroll
      for (int k = 0; k < NIN; k += 4) {
        float4 rk = *(const float4*)&r[k];
        acc += rk.x * Ws[(k + 0) * NOUT + j];
        acc += rk.y * Ws[(k + 1) * NOUT + j];
        acc += rk.z * Ws[(k + 2) * NOUT + j];
        acc += rk.w * Ws[(k + 3) * NOUT + j];
      }
      h[(size_t)v * NOUT + j] = acc;
      float pa = acc * a1s[j], pb = acc * a2s[j], pn = acc * acc;
      for (int o = 32; o > 0; o >>= 1) {
        pa += __shfl_down(pa, o, 64);
        pb += __shfl_down(pb, o, 64);
        pn += __shfl_down(pn, o, 64);
      }
      if (j == 0) { A[v] = pa; B[v] = pb; hn[v] = sqrtf(pn); }
    }
    __syncthreads();
  }
}

// ---------------------------------------------------------------------------
// Kernel 2: per edge: leaky-relu logits both directions -> l[]; degree-count
// atomics whose RETURN VALUE is the unit's within-segment rank (stored for
// atomic-free CSR placement in k_edge2).
// ---------------------------------------------------------------------------
__global__ __launch_bounds__(256) void k_edge1(
    const int* __restrict__ eb, const float* __restrict__ ef,
    const float* __restrict__ a, const float* __restrict__ A,
    const float* __restrict__ B, float* __restrict__ l,
    int* __restrict__ rank, int* __restrict__ count) {
  __shared__ float a3s[EIN];
  if (threadIdx.x < EIN) a3s[threadIdx.x] = a[128 + threadIdx.x];
  __syncthreads();
  int i = blockIdx.x * blockDim.x + threadIdx.x;
  if (i >= N_EDGES) return;
  int2 sd = ((const int2*)eb)[i];
  int s = clampi(sd.x), d = clampi(sd.y);
  const float4* efp = (const float4*)(ef + (size_t)i * EIN);
  float c = 0.f;
#pragma unroll
  for (int q = 0; q < 8; ++q) {
    float4 u = efp[q];
    c += u.x * a3s[4 * q + 0] + u.y * a3s[4 * q + 1] +
         u.z * a3s[4 * q + 2] + u.w * a3s[4 * q + 3];
  }
  float zf = A[s] + B[d] + c;  // forward: src=s, dst=d
  float zr = A[d] + B[s] + c;  // reverse: src=d, dst=s
  float lf = zf > 0.f ? zf : ALPHA * zf;
  float lr = zr > 0.f ? zr : ALPHA * zr;
  l[i] = lf;
  l[N_EDGES + i] = lr;
  rank[i] = atomicAdd(&count[s], 1);
  rank[N_EDGES + i] = atomicAdd(&count[d], 1);
}

// ---------------------------------------------------------------------------
// Kernel 3: single-block exclusive scan of count[50000] -> off.
// ---------------------------------------------------------------------------
__global__ __launch_bounds__(1024) void k_scan(const int* __restrict__ count,
                                               int* __restrict__ off) {
  __shared__ int ls[1024];
  int t = threadIdx.x;
  const int CH = 49;  // ceil(50000/1024)
  int start = t * CH, end = min(start + CH, N_NODES);
  int s = 0;
  for (int i = start; i < end; ++i) s += count[i];
  ls[t] = s;
  __syncthreads();
  for (int o = 1; o < 1024; o <<= 1) {
    int v = (t >= o) ? ls[t - o] : 0;
    __syncthreads();
    ls[t] += v;
    __syncthreads();
  }
  int run = (t == 0) ? 0 : ls[t - 1];
  for (int i = start; i < end; ++i) {
    off[i] = run;
    run += count[i];
  }
  if (t == 1023) off[N_NODES] = ls[1023];
}

// ---------------------------------------------------------------------------
// Kernel 4: pure CSR placement — single packed int2 (dst, raw logit l) store
// at off[src]+rank[u] (atomic-free).
// ---------------------------------------------------------------------------
__global__ __launch_bounds__(256) void k_edge2(
    const int* __restrict__ eb, const float* __restrict__ l,
    const int* __restrict__ rank, const int* __restrict__ off,
    int2* __restrict__ csr) {
  int u = blockIdx.x * blockDim.x + threadIdx.x;
  if (u >= N_UNITS) return;
  int s, d;
  if (u < N_EDGES) {
    int2 sd = ((const int2*)eb)[u];
    s = sd.x; d = sd.y;
  } else {
    int2 sd = ((const int2*)eb)[u - N_EDGES];
    s = sd.y; d = sd.x;
  }
  s = clampi(s);
  d = clampi(d);
  int pos = off[s] + rank[u];
  csr[pos] = make_int2(d, __float_as_int(l[u]));
}

// ---------------------------------------------------------------------------
// Kernel 5: one wave per node, single CSR pass, ZERO inner-loop DS ops:
//  - csr entries read with UNIFORM-address loads (hw broadcast) -> no
//    per-lane strided read, no ds_bpermute broadcasts.
//  - Se/L1/L2 computed redundantly by every lane (all lanes see all l_k)
//    -> no wave reductions for them; only the final ||msg|| reduce remains.
//  - segments processed in predicated batches of 8 (csr padded by 8
//    entries), next entry-batch prefetched over current row-batch consume.
//   msg = msgA - logS*msgB;  sum(an) = L1 - deg*logS;
//   sum(an^2) = L2 - 2*logS*L1 + deg*logS^2.
// Grid is exactly 12500*4 waves = 50000 nodes, so no early-return.
// ---------------------------------------------------------------------------
__global__ __launch_bounds__(256) void k_gather(
    const float* __restrict__ h, const float* __restrict__ hn,
    const int* __restrict__ off, const int2* __restrict__ csr,
    const float* __restrict__ scale_p, float* __restrict__ out,
    double* __restrict__ sums) {
  __shared__ double s1s[4], s2s[4];
  float scale = scale_p[0];
  int j = threadIdx.x & 63;
  int w = threadIdx.x >> 6;
  int v = blockIdx.x * 4 + w;  // grid exactly covers N_NODES
  int k0 = __builtin_amdgcn_readfirstlane(off[v]);
  int k1 = __builtin_amdgcn_readfirstlane(off[v + 1]);
  int deg = k1 - k0;
  float msgA = 0.f, msgB = 0.f, Se = 0.f, L1 = 0.f, L2 = 0.f;

  int2 E[8];
#pragma unroll
  for (int i = 0; i < 8; ++i) E[i] = csr[k0 + i];  // csr padded by 8 entries
  for (int kb = k0; kb < k1; kb += 8) {
    int2 C[8];
#pragma unroll
    for (int i = 0; i < 8; ++i) C[i] = E[i];
    if (kb + 8 < k1) {
#pragma unroll
      for (int i = 0; i < 8; ++i) E[i] = csr[kb + 8 + i];
    }
    float hv[8], lk[8];
#pragma unroll
    for (int i = 0; i < 8; ++i) {
      bool valid = (kb + i) < k1;
      int idx = valid ? C[i].x : v;          // safe row when masked
      lk[i] = valid ? __int_as_float(C[i].y) : 0.f;
      float hload = h[(size_t)idx * NOUT + j];
      hv[i] = valid ? hload : 0.f;
    }
#pragma unroll
    for (int i = 0; i < 8; ++i) {
      bool valid = (kb + i) < k1;
      float ex = __expf(lk[i]);
      Se += valid ? ex : 0.f;
      L1 += lk[i];
      L2 += lk[i] * lk[i];
      msgA += hv[i] * lk[i];
      msgB += hv[i];
    }
  }
  float logS = (deg > 0) ? logf(Se) : 0.f;
  float msg = msgA - logS * msgB;
  float nrm = msg * msg;
  for (int o = 32; o > 0; o >>= 1) nrm += __shfl_xor(nrm, o, 64);
  nrm = sqrtf(nrm);
  float fac = hn[v] * scale / fmaxf(nrm, 1e-12f);
  out[(size_t)v * 128 + j] = h[(size_t)v * NOUT + j];
  out[(size_t)v * 128 + 64 + j] = msg * fac;
  // variance partials per wave (closed form; identical in all lanes)
  if (j == 0) {
    double dls = (double)logS, dl1 = (double)L1, dl2 = (double)L2;
    double dd = (double)deg;
    s1s[w] = dl1 - dd * dls;
    s2s[w] = dl2 - 2.0 * dls * dl1 + dd * dls * dls;
  }
  __syncthreads();
  if (threadIdx.x == 0) {
    double t1 = s1s[0] + s1s[1] + s1s[2] + s1s[3];
    double t2 = s2s[0] + s2s[1] + s2s[2] + s2s[3];
    int bin = blockIdx.x & (NBINS - 1);
    atomicAdd(&sums[2 * bin], t1);
    atomicAdd(&sums[2 * bin + 1], t2);
  }
}

// ---------------------------------------------------------------------------
// Kernel 6: reduce 16 bins -> att_var -> out[6,400,000] (f32)
// ---------------------------------------------------------------------------
__global__ void k_var(const double* __restrict__ sums,
                      float* __restrict__ out) {
  if (threadIdx.x == 0 && blockIdx.x == 0) {
    double S1 = 0.0, S2 = 0.0;
#pragma unroll
    for (int i = 0; i < NBINS; ++i) {
      S1 += sums[2 * i];
      S2 += sums[2 * i + 1];
    }
    double M = (double)N_UNITS;
    double var = (S2 - S1 * S1 / M) / (M - 1.0);
    out[(size_t)N_NODES * 128] = (float)var;
  }
}

extern "C" void kernel_launch(void* const* d_in, const int* in_sizes, int n_in,
                              void* d_out, int out_size, void* d_ws,
                              size_t ws_size, hipStream_t stream) {
  const float* nf = (const float*)d_in[0];
  const float* ef = (const float*)d_in[1];
  const int* eb = (const int*)d_in[2];
  const float* W = (const float*)d_in[3];
  const float* b = (const float*)d_in[4];
  const float* a = (const float*)d_in[5];
  const float* scale_p = (const float*)d_in[6];
  float* out = (float*)d_out;  // 6,400,001 f32

  char* ws = (char*)d_ws;
  float* h = (float*)(ws + 0);              // 12,800,000 B
  float* l = (float*)(ws + 12800000);       //  3,200,000 B
  int* rank = (int*)(ws + 16000000);        //  3,200,000 B
  int2* csr = (int2*)(ws + 19200000);       //  6,400,000 B + 64 B overrun pad
  float* A = (float*)(ws + 25600064);       //    200,000 B
  float* B = (float*)(ws + 25800064);       //    200,000 B
  float* hn = (float*)(ws + 26000064);      //    200,000 B
  int* off = (int*)(ws + 26200064);         //    200,016 B (50001 + pad)
  int* count = (int*)(ws + 26400080);       //    200,000 B
  double* sums = (double*)(ws + 26600080);  //        256 B (16 bins x 2)

  // zero count + sums (contiguous)
  hipMemsetAsync(ws + 26400080, 0, 200256, stream);

  k_gemm<<<1024, 256, 0, stream>>>(nf, W, b, a, h, A, B, hn);
  k_edge1<<<(N_EDGES + 255) / 256, 256, 0, stream>>>(eb, ef, a, A, B, l, rank,
                                                     count);
  k_scan<<<1, 1024, 0, stream>>>(count, off);
  k_edge2<<<(N_UNITS + 255) / 256, 256, 0, stream>>>(eb, l, rank, off, csr);
  k_gather<<<12500, 256, 0, stream>>>(h, hn, off, csr, scale_p, out, sums);
  k_var<<<1, 64, 0, stream>>>(sums, out);
}

// Round 4
// 387.284 us; speedup vs baseline: 1.0474x; 1.0474x over previous
//
#include <hip/hip_runtime.h>

#define N_NODES 50000
#define NIN 128
#define NOUT 64
#define EIN 32
#define N_EDGES 400000
#define N_UNITS (2 * N_EDGES)
#define ALPHA 0.2f
#define NBINS 16

__device__ __forceinline__ int clampi(int x) {
  return min(max(x, 0), N_NODES - 1);
}

// round f32 -> bf16 (RNE), result in LOW 16 bits
__device__ __forceinline__ unsigned bf16_lo(float f) {
  unsigned u = __float_as_uint(f);
  return (u + 0x7FFFu + ((u >> 16) & 1u)) >> 16;
}
// round f32 -> bf16 (RNE), result left in HIGH 16 bits
__device__ __forceinline__ unsigned bf16_hi(float f) {
  unsigned u = __float_as_uint(f);
  return (u + 0x7FFFu + ((u >> 16) & 1u)) & 0xFFFF0000u;
}

// ---------------------------------------------------------------------------
// Kernel 1: h = node_fts @ W + b (f32); fused A = h.a1, B = h.a2, hn = ||h||;
// bf16 copy hb for the gather kernel.  Tail: grid-stride degree-count pass
// (rank[u] = within-segment arrival order) overlapped with the GEMM work of
// other blocks.
// ---------------------------------------------------------------------------
__global__ __launch_bounds__(256) void k_gemm(
    const float* __restrict__ nf, const float* __restrict__ W,
    const float* __restrict__ b, const float* __restrict__ a,
    const int* __restrict__ eb, float* __restrict__ h,
    unsigned short* __restrict__ hb, float* __restrict__ A,
    float* __restrict__ B, float* __restrict__ hn, int* __restrict__ rank,
    int* __restrict__ count) {
  __shared__ float Ws[NIN * NOUT];  // 32 KB
  __shared__ float bs[NOUT], a1s[NOUT], a2s[NOUT];
  __shared__ float rows[4][NIN];
  int t = threadIdx.x;
#pragma unroll
  for (int n = 0; n < 32; ++n) Ws[t + n * 256] = W[t + n * 256];
  if (t < 64) { bs[t] = b[t]; a1s[t] = a[t]; a2s[t] = a[64 + t]; }
  __syncthreads();
  int j = t & 63, local = t >> 6;
  for (int v0 = blockIdx.x * 4; v0 < N_NODES; v0 += gridDim.x * 4) {
    int vload = v0 + (t >> 6);
    if (vload < N_NODES) {
      float2 p = ((const float2*)(nf + (size_t)vload * NIN))[t & 63];
      ((float2*)rows[t >> 6])[t & 63] = p;
    }
    __syncthreads();
    int v = v0 + local;
    if (v < N_NODES) {
      float acc = bs[j];
      const float* r = rows[local];
#pragma unroll
      for (int k = 0; k < NIN; k += 4) {
        float4 rk = *(const float4*)&r[k];
        acc += rk.x * Ws[(k + 0) * NOUT + j];
        acc += rk.y * Ws[(k + 1) * NOUT + j];
        acc += rk.z * Ws[(k + 2) * NOUT + j];
        acc += rk.w * Ws[(k + 3) * NOUT + j];
      }
      h[(size_t)v * NOUT + j] = acc;
      hb[(size_t)v * NOUT + j] = (unsigned short)bf16_lo(acc);
      float pa = acc * a1s[j], pb = acc * a2s[j], pn = acc * acc;
      for (int o = 32; o > 0; o >>= 1) {
        pa += __shfl_down(pa, o, 64);
        pb += __shfl_down(pb, o, 64);
        pn += __shfl_down(pn, o, 64);
      }
      if (j == 0) { A[v] = pa; B[v] = pb; hn[v] = sqrtf(pn); }
    }
    __syncthreads();
  }
  // ---- degree count + rank (arrival order within segment) ----
  int stride = gridDim.x * blockDim.x;
  for (int u = blockIdx.x * blockDim.x + t; u < N_EDGES; u += stride) {
    int2 sd = ((const int2*)eb)[u];
    int s = clampi(sd.x), d = clampi(sd.y);
    rank[u] = atomicAdd(&count[s], 1);
    rank[N_EDGES + u] = atomicAdd(&count[d], 1);
  }
}

// ---------------------------------------------------------------------------
// Kernel 2: single-block exclusive scan of count[50000] -> off.
// ---------------------------------------------------------------------------
__global__ __launch_bounds__(1024) void k_scan(const int* __restrict__ count,
                                               int* __restrict__ off) {
  __shared__ int ls[1024];
  int t = threadIdx.x;
  const int CH = 49;  // ceil(50000/1024)
  int start = t * CH, end = min(start + CH, N_NODES);
  int s = 0;
  for (int i = start; i < end; ++i) s += count[i];
  ls[t] = s;
  __syncthreads();
  for (int o = 1; o < 1024; o <<= 1) {
    int v = (t >= o) ? ls[t - o] : 0;
    __syncthreads();
    ls[t] += v;
    __syncthreads();
  }
  int run = (t == 0) ? 0 : ls[t - 1];
  for (int i = start; i < end; ++i) {
    off[i] = run;
    run += count[i];
  }
  if (t == 1023) off[N_NODES] = ls[1023];
}

// ---------------------------------------------------------------------------
// Kernel 3 (fused old edge1+edge2): per edge compute leaky-relu logits both
// directions and scatter PACKED 4-byte csr entries (bf16(l) high | dst low)
// directly at off[src]+rank[u] — atomic-free, no l[] round-trip.
// ---------------------------------------------------------------------------
__global__ __launch_bounds__(256) void k_edge1(
    const int* __restrict__ eb, const float* __restrict__ ef,
    const float* __restrict__ a, const float* __restrict__ A,
    const float* __restrict__ B, const int* __restrict__ rank,
    const int* __restrict__ off, unsigned* __restrict__ csr) {
  __shared__ float a3s[EIN];
  if (threadIdx.x < EIN) a3s[threadIdx.x] = a[128 + threadIdx.x];
  __syncthreads();
  int i = blockIdx.x * blockDim.x + threadIdx.x;
  if (i >= N_EDGES) return;
  int2 sd = ((const int2*)eb)[i];
  int s = clampi(sd.x), d = clampi(sd.y);
  const float4* efp = (const float4*)(ef + (size_t)i * EIN);
  float c = 0.f;
#pragma unroll
  for (int q = 0; q < 8; ++q) {
    float4 u = efp[q];
    c += u.x * a3s[4 * q + 0] + u.y * a3s[4 * q + 1] +
         u.z * a3s[4 * q + 2] + u.w * a3s[4 * q + 3];
  }
  float zf = A[s] + B[d] + c;  // forward: src=s, dst=d
  float zr = A[d] + B[s] + c;  // reverse: src=d, dst=s
  float lf = zf > 0.f ? zf : ALPHA * zf;
  float lr = zr > 0.f ? zr : ALPHA * zr;
  csr[off[s] + rank[i]] = bf16_hi(lf) | (unsigned)d;
  csr[off[d] + rank[N_EDGES + i]] = bf16_hi(lr) | (unsigned)s;
}

// ---------------------------------------------------------------------------
// Kernel 4: one wave per node, single CSR pass, zero inner-loop DS ops.
//  - 4-byte csr entries read with UNIFORM-address loads (hw broadcast).
//  - h gathered from the bf16 copy hb (128 B/row, ~half the EA bytes; the
//    scattered-EA path plateaus ~1 TB/s so bytes == time).
//  - Se/L1/L2 computed redundantly per-lane (no wave reductions needed).
//   msg = msgA - logS*msgB;  sum(an) = L1 - deg*logS;
//   sum(an^2) = L2 - 2*logS*L1 + deg*logS^2.
// Grid is exactly 12500*4 waves = 50000 nodes, so no early-return.
// ---------------------------------------------------------------------------
__global__ __launch_bounds__(256) void k_gather(
    const float* __restrict__ h, const unsigned short* __restrict__ hb,
    const float* __restrict__ hn, const int* __restrict__ off,
    const unsigned* __restrict__ csr, const float* __restrict__ scale_p,
    float* __restrict__ out, double* __restrict__ sums) {
  __shared__ double s1s[4], s2s[4];
  float scale = scale_p[0];
  int j = threadIdx.x & 63;
  int w = threadIdx.x >> 6;
  int v = blockIdx.x * 4 + w;  // grid exactly covers N_NODES
  int k0 = __builtin_amdgcn_readfirstlane(off[v]);
  int k1 = __builtin_amdgcn_readfirstlane(off[v + 1]);
  int deg = k1 - k0;
  float msgA = 0.f, msgB = 0.f, Se = 0.f, L1 = 0.f, L2 = 0.f;

  unsigned E[8];
#pragma unroll
  for (int i = 0; i < 8; ++i) E[i] = csr[k0 + i];  // csr padded by 8 entries
  for (int kb = k0; kb < k1; kb += 8) {
    unsigned C[8];
#pragma unroll
    for (int i = 0; i < 8; ++i) C[i] = E[i];
    if (kb + 8 < k1) {
#pragma unroll
      for (int i = 0; i < 8; ++i) E[i] = csr[kb + 8 + i];
    }
    float hv[8], lk[8];
#pragma unroll
    for (int i = 0; i < 8; ++i) {
      bool valid = (kb + i) < k1;
      int idx = valid ? (int)(C[i] & 0xFFFFu) : v;  // safe row when masked
      lk[i] = valid ? __uint_as_float(C[i] & 0xFFFF0000u) : 0.f;
      unsigned short us = hb[(size_t)idx * NOUT + j];
      hv[i] = valid ? __uint_as_float((unsigned)us << 16) : 0.f;
    }
#pragma unroll
    for (int i = 0; i < 8; ++i) {
      bool valid = (kb + i) < k1;
      float ex = __expf(lk[i]);
      Se += valid ? ex : 0.f;
      L1 += lk[i];
      L2 += lk[i] * lk[i];
      msgA += hv[i] * lk[i];
      msgB += hv[i];
    }
  }
  float logS = (deg > 0) ? logf(Se) : 0.f;
  float msg = msgA - logS * msgB;
  float nrm = msg * msg;
  for (int o = 32; o > 0; o >>= 1) nrm += __shfl_xor(nrm, o, 64);
  nrm = sqrtf(nrm);
  float fac = hn[v] * scale / fmaxf(nrm, 1e-12f);
  out[(size_t)v * 128 + j] = h[(size_t)v * NOUT + j];  // exact f32 copy
  out[(size_t)v * 128 + 64 + j] = msg * fac;
  // variance partials per wave (closed form; identical in all lanes)
  if (j == 0) {
    double dls = (double)logS, dl1 = (double)L1, dl2 = (double)L2;
    double dd = (double)deg;
    s1s[w] = dl1 - dd * dls;
    s2s[w] = dl2 - 2.0 * dls * dl1 + dd * dls * dls;
  }
  __syncthreads();
  if (threadIdx.x == 0) {
    double t1 = s1s[0] + s1s[1] + s1s[2] + s1s[3];
    double t2 = s2s[0] + s2s[1] + s2s[2] + s2s[3];
    int bin = blockIdx.x & (NBINS - 1);
    atomicAdd(&sums[2 * bin], t1);
    atomicAdd(&sums[2 * bin + 1], t2);
  }
}

// ---------------------------------------------------------------------------
// Kernel 5: reduce 16 bins -> att_var -> out[6,400,000] (f32)
// ---------------------------------------------------------------------------
__global__ void k_var(const double* __restrict__ sums,
                      float* __restrict__ out) {
  if (threadIdx.x == 0 && blockIdx.x == 0) {
    double S1 = 0.0, S2 = 0.0;
#pragma unroll
    for (int i = 0; i < NBINS; ++i) {
      S1 += sums[2 * i];
      S2 += sums[2 * i + 1];
    }
    double M = (double)N_UNITS;
    double var = (S2 - S1 * S1 / M) / (M - 1.0);
    out[(size_t)N_NODES * 128] = (float)var;
  }
}

extern "C" void kernel_launch(void* const* d_in, const int* in_sizes, int n_in,
                              void* d_out, int out_size, void* d_ws,
                              size_t ws_size, hipStream_t stream) {
  const float* nf = (const float*)d_in[0];
  const float* ef = (const float*)d_in[1];
  const int* eb = (const int*)d_in[2];
  const float* W = (const float*)d_in[3];
  const float* b = (const float*)d_in[4];
  const float* a = (const float*)d_in[5];
  const float* scale_p = (const float*)d_in[6];
  float* out = (float*)d_out;  // 6,400,001 f32

  char* ws = (char*)d_ws;
  float* h = (float*)(ws + 0);                    // 12,800,000 B (f32)
  unsigned short* hb = (unsigned short*)(ws + 12800000);  // 6,400,000 B (bf16)
  unsigned* csr = (unsigned*)(ws + 19200000);     // 3,200,000 B + 32 B pad
  int* rank = (int*)(ws + 22400032);              // 3,200,000 B
  float* A = (float*)(ws + 25600032);             //   200,000 B
  float* B = (float*)(ws + 25800032);             //   200,000 B
  float* hn = (float*)(ws + 26000032);            //   200,000 B
  int* off = (int*)(ws + 26200032);               //   200,016 B (50001 + pad)
  int* count = (int*)(ws + 26400048);             //   200,000 B
  double* sums = (double*)(ws + 26600048);        //       256 B (16 bins x 2)

  // zero count + sums (contiguous)
  hipMemsetAsync(ws + 26400048, 0, 200256, stream);

  k_gemm<<<1024, 256, 0, stream>>>(nf, W, b, a, eb, h, hb, A, B, hn, rank,
                                   count);
  k_scan<<<1, 1024, 0, stream>>>(count, off);
  k_edge1<<<(N_EDGES + 255) / 256, 256, 0, stream>>>(eb, ef, a, A, B, rank,
                                                     off, csr);
  k_gather<<<12500, 256, 0, stream>>>(h, hb, hn, off, csr, scale_p, out, sums);
  k_var<<<1, 64, 0, stream>>>(sums, out);
}